// Round 2
// baseline (514.283 us; speedup 1.0000x reference)
//
#include <hip/hip_runtime.h>
#include <hip/hip_bf16.h>
#include <cstdint>
#include <cstddef>

#define N_TOK   8192
#define D_MODEL 1024
#define D_FFN   4096
#define K_TOP   512
#define NHALF   2048   // FFN half-width processed per round

typedef __bf16 bf16_t;
typedef __bf16 bf16x8 __attribute__((ext_vector_type(8)));
typedef __bf16 bf16x4 __attribute__((ext_vector_type(4)));
typedef float  f32x4  __attribute__((ext_vector_type(4)));

// ---------------- aux kernels ----------------

__global__ void cvt_f32_bf16(const float* __restrict__ in, bf16_t* __restrict__ out, int n4) {
  int i = blockIdx.x * blockDim.x + threadIdx.x;
  if (i < n4) {
    const f32x4 v = ((const f32x4*)in)[i];
    bf16x4 o;
    o[0] = (bf16_t)v[0]; o[1] = (bf16_t)v[1]; o[2] = (bf16_t)v[2]; o[3] = (bf16_t)v[3];
    ((bf16x4*)out)[i] = o;
  }
}

// in: [rows][cols] f32  ->  out: [cols][rows] bf16   (B^T layout for GEMM)
__global__ void transpose_cvt(const float* __restrict__ in, bf16_t* __restrict__ out,
                              int rows, int cols) {
  __shared__ float tile[32][33];
  const int tx = threadIdx.x, ty = threadIdx.y;
  const int x = blockIdx.x * 32 + tx;
#pragma unroll
  for (int i = 0; i < 32; i += 8) {
    int y = blockIdx.y * 32 + ty + i;
    tile[ty + i][tx] = in[(size_t)y * cols + x];
  }
  __syncthreads();
  const int xo = blockIdx.y * 32 + tx;
#pragma unroll
  for (int i = 0; i < 32; i += 8) {
    int yo = blockIdx.x * 32 + ty + i;
    out[(size_t)yo * rows + xo] = (bf16_t)tile[tx][ty + i];
  }
}

// multiplicity counts, packed 8 x 4-bit nibbles per u32 (multiplicity < 16:
// indices ~ Poisson(0.125) per bin, P(>=16) ~ 1e-28/bin -> safe)
__global__ void count_scatter_nib(const int* __restrict__ idx, unsigned int* __restrict__ M) {
  int t = blockIdx.x * blockDim.x + threadIdx.x;
  if (t < N_TOK * K_TOP) {
    int row = t >> 9;  // / K_TOP
    int j = idx[t];
    atomicAdd(&M[(size_t)row * (D_FFN / 8) + (j >> 3)], 1u << ((j & 7) * 4));
  }
}

// ---------------- GEMM common ----------------

#define BM 128
#define BN 128
#define BK 32

__device__ __forceinline__ void gload_lds16(const void* g, void* l) {
#if __has_builtin(__builtin_amdgcn_global_load_lds)
  __builtin_amdgcn_global_load_lds((__attribute__((address_space(1))) void*)(g),
                                   (__attribute__((address_space(3))) void*)(l), 16, 0, 0);
#else
  *(bf16x8*)l = *(const bf16x8*)g;  // fallback: reg staging
#endif
}

// GEMM1: G,U = A(8192x1024) * {Bg,Bu}^T over one FFN half, fused epilogue
// Z = cnt * silu(G) * U (bf16), Z is [N_TOK][NHALF]
__global__ __launch_bounds__(256) void gemm_gateup(
    const bf16_t* __restrict__ A,    // [N_TOK][D_MODEL]
    const bf16_t* __restrict__ Bg,   // [D_FFN][D_MODEL]  (w_gate^T)
    const bf16_t* __restrict__ Bu,   // [D_FFN][D_MODEL]  (w_up^T)
    const unsigned int* __restrict__ cnt,  // [N_TOK][D_FFN/8] nibble counts
    bf16_t* __restrict__ Z,          // [N_TOK][NHALF]
    int n_base)                      // 0 or NHALF
{
  __shared__ alignas(16) bf16_t As[BM * BK];
  __shared__ alignas(16) bf16_t Bgs[BN * BK];
  __shared__ alignas(16) bf16_t Bus[BN * BK];

  const int m0 = blockIdx.x * BM;
  const int n0 = blockIdx.y * BN;        // local within half
  const int t = threadIdx.x;
  const int lane = t & 63;
  const int w = t >> 6;
  const int wr = w >> 1, wc = w & 1;
  const int l15 = lane & 15;
  const int kk = (lane >> 4) * 8;

  f32x4 accg[4][4] = {};
  f32x4 accu[4][4] = {};

  for (int k0 = 0; k0 < D_MODEL; k0 += BK) {
#pragma unroll
    for (int r = 0; r < 2; ++r) {
      const int e = r * 256 + t;
      const int row = e >> 2;          // 4 threads per 32-elem row
      const int col = (e & 3) * 8;
      gload_lds16(A  + (size_t)(m0 + row) * D_MODEL + k0 + col, As  + e * 8);
      gload_lds16(Bg + (size_t)(n_base + n0 + row) * D_MODEL + k0 + col, Bgs + e * 8);
      gload_lds16(Bu + (size_t)(n_base + n0 + row) * D_MODEL + k0 + col, Bus + e * 8);
    }
    __syncthreads();

    bf16x8 af[4], bgf[4], buf[4];
#pragma unroll
    for (int m = 0; m < 4; ++m)
      af[m] = *(const bf16x8*)(As + (wr * 64 + m * 16 + l15) * BK + kk);
#pragma unroll
    for (int n = 0; n < 4; ++n) {
      bgf[n] = *(const bf16x8*)(Bgs + (wc * 64 + n * 16 + l15) * BK + kk);
      buf[n] = *(const bf16x8*)(Bus + (wc * 64 + n * 16 + l15) * BK + kk);
    }
#pragma unroll
    for (int m = 0; m < 4; ++m)
#pragma unroll
      for (int n = 0; n < 4; ++n) {
        accg[m][n] = __builtin_amdgcn_mfma_f32_16x16x32_bf16(af[m], bgf[n], accg[m][n], 0, 0, 0);
        accu[m][n] = __builtin_amdgcn_mfma_f32_16x16x32_bf16(af[m], buf[n], accu[m][n], 0, 0, 0);
      }
    __syncthreads();
  }

  // epilogue: Z = cnt * u * silu(g)   (C/D map: col=lane&15, row=(lane>>4)*4+j)
#pragma unroll
  for (int m = 0; m < 4; ++m) {
#pragma unroll
    for (int n = 0; n < 4; ++n) {
      const int colL = n0 + wc * 64 + n * 16 + l15;   // local col within half
      const int jg = n_base + colL;                   // global FFN index
#pragma unroll
      for (int j = 0; j < 4; ++j) {
        const int row = m0 + wr * 64 + m * 16 + (lane >> 4) * 4 + j;
        float g = accg[m][n][j];
        float u = accu[m][n][j];
        unsigned int cw = cnt[(size_t)row * (D_FFN / 8) + (jg >> 3)];
        float c = (float)((cw >> ((jg & 7) * 4)) & 15u);
        float z = c * u * (g / (1.0f + __expf(-g)));
        Z[(size_t)row * NHALF + colL] = (bf16_t)z;
      }
    }
  }
}

// GEMM2: out (+)= Z(8192xNHALF) * w_down[k_base:k_base+NHALF, :]
// B given as w_down^T [D_MODEL][D_FFN]
__global__ __launch_bounds__(256) void gemm_down(
    const bf16_t* __restrict__ A,    // Z [N_TOK][NHALF]
    const bf16_t* __restrict__ B,    // [D_MODEL][D_FFN]  (w_down^T)
    float* __restrict__ C,           // [N_TOK][D_MODEL]
    int k_base, int accum)
{
  __shared__ alignas(16) bf16_t As[BM * BK];
  __shared__ alignas(16) bf16_t Bs[BN * BK];

  const int m0 = blockIdx.x * BM;
  const int n0 = blockIdx.y * BN;
  const int t = threadIdx.x;
  const int lane = t & 63;
  const int w = t >> 6;
  const int wr = w >> 1, wc = w & 1;
  const int l15 = lane & 15;
  const int kk = (lane >> 4) * 8;

  f32x4 acc[4][4] = {};

  for (int k0 = 0; k0 < NHALF; k0 += BK) {
#pragma unroll
    for (int r = 0; r < 2; ++r) {
      const int e = r * 256 + t;
      const int row = e >> 2;
      const int col = (e & 3) * 8;
      gload_lds16(A + (size_t)(m0 + row) * NHALF + k0 + col, As + e * 8);
      gload_lds16(B + (size_t)(n0 + row) * D_FFN + k_base + k0 + col, Bs + e * 8);
    }
    __syncthreads();

    bf16x8 af[4], bf[4];
#pragma unroll
    for (int m = 0; m < 4; ++m)
      af[m] = *(const bf16x8*)(As + (wr * 64 + m * 16 + l15) * BK + kk);
#pragma unroll
    for (int n = 0; n < 4; ++n)
      bf[n] = *(const bf16x8*)(Bs + (wc * 64 + n * 16 + l15) * BK + kk);
#pragma unroll
    for (int m = 0; m < 4; ++m)
#pragma unroll
      for (int n = 0; n < 4; ++n)
        acc[m][n] = __builtin_amdgcn_mfma_f32_16x16x32_bf16(af[m], bf[n], acc[m][n], 0, 0, 0);
    __syncthreads();
  }

#pragma unroll
  for (int m = 0; m < 4; ++m) {
#pragma unroll
    for (int n = 0; n < 4; ++n) {
      const int col = n0 + wc * 64 + n * 16 + l15;
#pragma unroll
      for (int j = 0; j < 4; ++j) {
        const int row = m0 + wr * 64 + m * 16 + (lane >> 4) * 4 + j;
        const size_t off = (size_t)row * D_MODEL + col;
        float prev = accum ? C[off] : 0.0f;
        C[off] = prev + acc[m][n][j];
      }
    }
  }
}

// ---------------- launch ----------------

extern "C" void kernel_launch(void* const* d_in, const int* in_sizes, int n_in,
                              void* d_out, int out_size, void* d_ws, size_t ws_size,
                              hipStream_t stream) {
  const float* x  = (const float*)d_in[0];
  const int*   idx = (const int*)d_in[1];
  const float* wg = (const float*)d_in[2];
  const float* wu = (const float*)d_in[3];
  const float* wd = (const float*)d_in[4];
  float* out = (float*)d_out;

  char* ws = (char*)d_ws;
  const size_t SZ_XB  = (size_t)N_TOK * D_MODEL * 2;   // 16 MB
  const size_t SZ_W   = (size_t)D_MODEL * D_FFN * 2;   //  8 MB each
  const size_t SZ_CNT = (size_t)N_TOK * D_FFN / 2;     // 16 MB (4-bit counts)
  bf16_t* xb  = (bf16_t*)(ws);
  bf16_t* wgT = (bf16_t*)(ws + SZ_XB);
  bf16_t* wuT = (bf16_t*)(ws + SZ_XB + SZ_W);
  bf16_t* wdT = (bf16_t*)(ws + SZ_XB + 2 * SZ_W);
  unsigned int* cnt = (unsigned int*)(ws + SZ_XB + 3 * SZ_W);
  bf16_t* Z   = (bf16_t*)(ws + SZ_XB + 3 * SZ_W + SZ_CNT);  // [N_TOK][NHALF]
  // total ws use: 16 + 24 + 16 + 32 = 88 MB

  hipMemsetAsync(cnt, 0, SZ_CNT, stream);

  cvt_f32_bf16<<<(N_TOK * D_MODEL / 4 + 255) / 256, 256, 0, stream>>>(x, xb, N_TOK * D_MODEL / 4);
  transpose_cvt<<<dim3(D_FFN / 32, D_MODEL / 32), dim3(32, 8), 0, stream>>>(wg, wgT, D_MODEL, D_FFN);
  transpose_cvt<<<dim3(D_FFN / 32, D_MODEL / 32), dim3(32, 8), 0, stream>>>(wu, wuT, D_MODEL, D_FFN);
  transpose_cvt<<<dim3(D_MODEL / 32, D_FFN / 32), dim3(32, 8), 0, stream>>>(wd, wdT, D_FFN, D_MODEL);
  count_scatter_nib<<<(N_TOK * K_TOP + 255) / 256, 256, 0, stream>>>(idx, cnt);

  // two FFN halves, Z buffer reused (stream-ordered)
  gemm_gateup<<<dim3(N_TOK / BM, NHALF / BN), 256, 0, stream>>>(xb, wgT, wuT, cnt, Z, 0);
  gemm_down<<<dim3(N_TOK / BM, D_MODEL / BN), 256, 0, stream>>>(Z, wdT, out, 0, 0);
  gemm_gateup<<<dim3(N_TOK / BM, NHALF / BN), 256, 0, stream>>>(xb, wgT, wuT, cnt, Z, NHALF);
  gemm_down<<<dim3(N_TOK / BM, D_MODEL / BN), 256, 0, stream>>>(Z, wdT, out, NHALF, 1);
}